// Round 12
// baseline (81.446 us; speedup 1.0000x reference)
//
#include <hip/hip_runtime.h>
#include <hip/hip_fp16.h>
#include <stdint.h>

#define SS 256
#define FAR_F 100.0f
#define REG 32             // region size in px
#define NREG 64            // regions per batch (8x8)
#define NCH 3              // face chunks
#define CAPP 448           // partial-face pool capacity
#define CAPQ 352           // per-quadrant partial list capacity (multiple of 4)
#define CAPFQ 224          // per-quadrant full list capacity
#define OVN  96            // overflow capacity
#define DEFN 32            // per-wave deferred-ambiguity capacity

struct __align__(16) PackedCoef {
    float4 q0;  // A0,B0,C0,A1   (edge coefs premultiplied by inv_area)
    float4 q1;  // B1,C1,Zx,Zy   (zinv = Z0 + Zx*px + Zy*py)
    float4 q2;  // Z0, e_face, bits(bbox), bits(faceid)
};

// ---------------- prep: per (b,f) packed coefficients + bbox ----------------
__global__ void nmr_prep(const float* __restrict__ verts,
                         const int* __restrict__ faces,
                         PackedCoef* __restrict__ pc,
                         uint32_t* __restrict__ bbx,
                         int B, int N, int F)
{
#pragma clang fp contract(off)
    int idx = blockIdx.x * blockDim.x + threadIdx.x;
    if (idx >= B * F) return;
    int b = idx / F;
    int f = idx - b * F;

    int i0 = faces[3 * f + 0], i1 = faces[3 * f + 1], i2 = faces[3 * f + 2];
    const float* vb = verts + (size_t)(3 * N) * b;
    const float EZ = -1.7320508075688772f;  // f32(EYE_Z)

    float x0 = vb[3 * i0 + 0], y0 = -vb[3 * i0 + 1], z0 = vb[3 * i0 + 2] - EZ;
    float x1 = vb[3 * i1 + 0], y1 = -vb[3 * i1 + 1], z1 = vb[3 * i1 + 2] - EZ;
    float x2 = vb[3 * i2 + 0], y2 = -vb[3 * i2 + 1], z2 = vb[3 * i2 + 2] - EZ;

    float area = (x1 - x0) * (y2 - y0) - (x2 - x0) * (y1 - y0);
    bool ok = fabsf(area) > 1e-7f;
    float ia = ok ? (1.0f / area) : 0.0f;

    float A0 = (x1 * y2 - x2 * y1) * ia, B0 = (y1 - y2) * ia, C0 = (x2 - x1) * ia;
    float A1 = (x2 * y0 - x0 * y2) * ia, B1 = (y2 - y0) * ia, C1 = (x0 - x2) * ia;
    float rz0 = 1.0f / z0, rz1 = 1.0f / z1, rz2 = 1.0f / z2;
    float d0 = rz0 - rz2, d1 = rz1 - rz2;
    float Z0 = rz2 + A0 * d0 + A1 * d1;
    float Zx = B0 * d0 + B1 * d1;
    float Zy = C0 * d0 + C1 * d1;
    // rigorous per-face ambiguity half-width (|px|,|py|<1)
    float S = fabsf(A0) + fabsf(B0) + fabsf(C0) + fabsf(A1) + fabsf(B1) + fabsf(C1) + 1.0f;
    float ef = 3e-6f * S;

    uint32_t bb = 255u | (0u << 8) | (255u << 16) | (0u << 24);
    if (ok) {
        float xmn = fminf(x0, fminf(x1, x2)), xmx = fmaxf(x0, fmaxf(x1, x2));
        float ymn = fminf(y0, fminf(y1, y2)), ymx = fmaxf(y0, fmaxf(y1, y2));
        int jlo = (int)floorf(128.0f * (xmn + 1.0f) - 0.5f) - 1;
        int jhi = (int)ceilf (128.0f * (xmx + 1.0f) - 0.5f) + 1;
        int ilo = (int)floorf((255.0f - 256.0f * ymx) * 0.5f) - 1;
        int ihi = (int)ceilf ((255.0f - 256.0f * ymn) * 0.5f) + 1;
        jlo = max(0, min(255, jlo)); jhi = max(0, min(255, jhi));
        ilo = max(0, min(255, ilo)); ihi = max(0, min(255, ihi));
        if (jhi >= jlo && ihi >= ilo)
            bb = (uint32_t)jlo | ((uint32_t)jhi << 8) | ((uint32_t)ilo << 16) | ((uint32_t)ihi << 24);
    }

    PackedCoef c;
    c.q0 = make_float4(A0, B0, C0, A1);
    c.q1 = make_float4(B1, C1, Zx, Zy);
    c.q2 = make_float4(Z0, ef, __uint_as_float(bb), __uint_as_float((uint32_t)f));
    pc[idx] = c;
    bbx[idx] = bb;
}

// exact numpy-order decision + accumulate (deferred-ambiguity / amb paths)
__device__ __forceinline__ void exact_body(
    float Zx, float Zy, float Z0, int fid,
    float px, float py0, float py1, float py2, float py3,
    const float* __restrict__ verts, const int* __restrict__ faces, int N, int b,
    float& best0, float& best1, float& best2, float& best3)
{
#pragma clang fp contract(off)
    float zbv = __builtin_fmaf(Zx, px, Z0);
    float zi0 = __builtin_fmaf(Zy, py0, zbv);
    float zi1 = __builtin_fmaf(Zy, py1, zbv);
    float zi2 = __builtin_fmaf(Zy, py2, zbv);
    float zi3 = __builtin_fmaf(Zy, py3, zbv);
    fid = __builtin_amdgcn_readfirstlane(fid);
    int i0f = faces[3 * fid + 0], i1f = faces[3 * fid + 1], i2f = faces[3 * fid + 2];
    const float* vb = verts + (size_t)(3 * N) * b;
    float x0 = vb[3 * i0f + 0], y0 = -vb[3 * i0f + 1];
    float x1 = vb[3 * i1f + 0], y1 = -vb[3 * i1f + 1];
    float x2 = vb[3 * i2f + 0], y2 = -vb[3 * i2f + 1];
    float area = (x1 - x0) * (y2 - y0) - (x2 - x0) * (y1 - y0);
    float ia = 1.0f / area;   // staged faces are non-degenerate
    float a0 = x1 * y2 - x2 * y1, b0e = y1 - y2, c0e = x2 - x1;
    float a1 = x2 * y0 - x0 * y2, b1e = y2 - y0, c1e = x0 - x2;
    float e0b = a0 + b0e * px;
    float e1b = a1 + b1e * px;
    { float u0 = (e0b + c0e * py0) * ia, u1 = (e1b + c1e * py0) * ia;
      if (fminf(u0, fminf(u1, (1.0f - u0) - u1)) >= 0.0f) best0 = fmaxf(best0, zi0); }
    { float u0 = (e0b + c0e * py1) * ia, u1 = (e1b + c1e * py1) * ia;
      if (fminf(u0, fminf(u1, (1.0f - u0) - u1)) >= 0.0f) best1 = fmaxf(best1, zi1); }
    { float u0 = (e0b + c0e * py2) * ia, u1 = (e1b + c1e * py2) * ia;
      if (fminf(u0, fminf(u1, (1.0f - u0) - u1)) >= 0.0f) best2 = fmaxf(best2, zi2); }
    { float u0 = (e0b + c0e * py3) * ia, u1 = (e1b + c1e * py3) * ia;
      if (fminf(u0, fminf(u1, (1.0f - u0) - u1)) >= 0.0f) best3 = fmaxf(best3, zi3); }
}

// full body from global records (overflow path only)
__device__ __forceinline__ void face_body(
    float4 q0, float4 q1, float4 q2,
    float px, float py0, float py1, float py2, float py3,
    const float* __restrict__ verts, const int* __restrict__ faces, int N, int b,
    float& best0, float& best1, float& best2, float& best3)
{
#pragma clang fp contract(off)
    const float ef = q2.y;
    float w0b = __builtin_fmaf(q0.y, px, q0.x);
    float w1b = __builtin_fmaf(q1.x, px, q0.w);
    float zbv = __builtin_fmaf(q1.z, px, q2.x);
    float w0_0 = __builtin_fmaf(q0.z, py0, w0b), w1_0 = __builtin_fmaf(q1.y, py0, w1b);
    float w0_1 = __builtin_fmaf(q0.z, py1, w0b), w1_1 = __builtin_fmaf(q1.y, py1, w1b);
    float w0_2 = __builtin_fmaf(q0.z, py2, w0b), w1_2 = __builtin_fmaf(q1.y, py2, w1b);
    float w0_3 = __builtin_fmaf(q0.z, py3, w0b), w1_3 = __builtin_fmaf(q1.y, py3, w1b);
    float m0 = fminf(w0_0, fminf(w1_0, (1.0f - w0_0) - w1_0));
    float m1 = fminf(w0_1, fminf(w1_1, (1.0f - w0_1) - w1_1));
    float m2 = fminf(w0_2, fminf(w1_2, (1.0f - w0_2) - w1_2));
    float m3 = fminf(w0_3, fminf(w1_3, (1.0f - w0_3) - w1_3));
    float zi0 = __builtin_fmaf(q1.w, py0, zbv);
    float zi1 = __builtin_fmaf(q1.w, py1, zbv);
    float zi2 = __builtin_fmaf(q1.w, py2, zbv);
    float zi3 = __builtin_fmaf(q1.w, py3, zbv);
    bool amb = (fabsf(m0) <= ef) | (fabsf(m1) <= ef) | (fabsf(m2) <= ef) | (fabsf(m3) <= ef);
    if (__any(amb)) {
        exact_body(q1.z, q1.w, q2.x, (int)__float_as_uint(q2.w),
                   px, py0, py1, py2, py3, verts, faces, N, b, best0, best1, best2, best3);
        return;
    }
    best0 = (m0 > ef) ? fmaxf(best0, zi0) : best0;
    best1 = (m1 > ef) ? fmaxf(best1, zi1) : best1;
    best2 = (m2 > ef) ? fmaxf(best2, zi2) : best2;
    best3 = (m3 > ef) ? fmaxf(best3, zi3) : best3;
}

__device__ __forceinline__ float wave_min_f(float x) {
    #pragma unroll
    for (int m = 1; m < 64; m <<= 1) x = fminf(x, __shfl_xor(x, m));
    return x;
}

// ---------------- raster: block = (batch, 32x32 region, face-chunk) ----------------
__global__ __launch_bounds__(256, 4) void nmr_raster(
    const PackedCoef* __restrict__ pc,
    const uint32_t* __restrict__ bbx,
    const float* __restrict__ verts,
    const int* __restrict__ faces,
    uint32_t* __restrict__ zu,
    int B, int N, int F, int CH)
{
#pragma clang fp contract(off)
    __shared__ float4   pool[2 * CAPP];               // partial: edge coefs + (B1,C1,Zx,Zy)
    __shared__ uint2    zef[CAPP];                    // partial: Z0 bits, fid<<16|ef_f16
    __shared__ float4   qfull[4][CAPFQ];              // full-in-quadrant: Z0,Zx,Zy,key
    __shared__ __align__(16) uint32_t qpart[4][CAPQ]; // partial per-quadrant: key|poolidx
    __shared__ uint16_t ovl[OVN];                     // overflow face ids (global fallback)
    __shared__ uint16_t dlist[4][DEFN];               // per-wave deferred-amb pool idx
    __shared__ uint32_t thrq[4];                      // per-quadrant full-face zmin floor (bits)
    __shared__ int qcnt[4], qfcnt[4], cnt_p, cnt_o;

    const int tid = threadIdx.x;
    const int bid = blockIdx.x;
    const int ch = bid % NCH; int t = bid / NCH;
    const int reg = t % NREG; const int b = t / NREG;
    const int rj0 = (reg & 7) * REG;
    const int ri0 = (reg >> 3) * REG;

    if (tid == 0) { cnt_p = 0; cnt_o = 0; }
    if (tid < 4) { qcnt[tid] = 0; qfcnt[tid] = 0; thrq[tid] = 0u; }
    __syncthreads();

    // ---- phase 1: cull -> per-quadrant classify -> stage ----
    const int f0 = ch * CH, f1 = min(F, f0 + CH);
    const uint32_t* bb = bbx + (size_t)b * F;
    const PackedCoef* pb = pc + (size_t)b * F;

    // quadrant corner coords (x: cols rj0, rj0+15 | rj0+16, rj0+31; y likewise)
    const float cx0 = (float)(2 * rj0 + 1 - SS) * (1.0f / SS);
    const float cx1 = (float)(2 * (rj0 + 15) + 1 - SS) * (1.0f / SS);
    const float cx2 = (float)(2 * (rj0 + 16) + 1 - SS) * (1.0f / SS);
    const float cx3 = (float)(2 * (rj0 + 31) + 1 - SS) * (1.0f / SS);
    const float cy0 = (float)(SS - 1 - 2 * ri0) * (1.0f / SS);
    const float cy1 = (float)(SS - 1 - 2 * (ri0 + 15)) * (1.0f / SS);
    const float cy2 = (float)(SS - 1 - 2 * (ri0 + 16)) * (1.0f / SS);
    const float cy3 = (float)(SS - 1 - 2 * (ri0 + 31)) * (1.0f / SS);

    for (int f = f0 + tid; f < f1; f += 256) {
        uint32_t v = bb[f];
        int jlo = v & 255, jhi = (v >> 8) & 255, ilo = (v >> 16) & 255, ihi = (int)(v >> 24);
        if (jlo > rj0 + REG - 1 || jhi < rj0 || ilo > ri0 + REG - 1 || ihi < ri0) continue;
        PackedCoef P = pb[f];
        const float A0 = P.q0.x, B0 = P.q0.y, C0 = P.q0.z;
        const float A1 = P.q0.w, B1 = P.q1.x, C1 = P.q1.y;
        const float Zx = P.q1.z, Zy = P.q1.w, Z0 = P.q2.x, ef = P.q2.y;
        const float A2 = (1.0f - A0) - A1, B2 = (0.0f - B0) - B1, C2 = (0.0f - C0) - C1;
        const float Rm = 2.0f * ef;

        // separable per-quadrant bounds for 3 edges
        float bn[3][2], bX[3][2], tn[3][2], tX[3][2];
        {
            float e_b0, e_b1, e_b2, e_b3, e_t0, e_t1, e_t2, e_t3;
            // edge 0
            e_b0 = __builtin_fmaf(B0, cx0, A0); e_b1 = __builtin_fmaf(B0, cx1, A0);
            e_b2 = __builtin_fmaf(B0, cx2, A0); e_b3 = __builtin_fmaf(B0, cx3, A0);
            e_t0 = C0 * cy0; e_t1 = C0 * cy1; e_t2 = C0 * cy2; e_t3 = C0 * cy3;
            bn[0][0] = fminf(e_b0, e_b1); bX[0][0] = fmaxf(e_b0, e_b1);
            bn[0][1] = fminf(e_b2, e_b3); bX[0][1] = fmaxf(e_b2, e_b3);
            tn[0][0] = fminf(e_t0, e_t1); tX[0][0] = fmaxf(e_t0, e_t1);
            tn[0][1] = fminf(e_t2, e_t3); tX[0][1] = fmaxf(e_t2, e_t3);
            // edge 1
            e_b0 = __builtin_fmaf(B1, cx0, A1); e_b1 = __builtin_fmaf(B1, cx1, A1);
            e_b2 = __builtin_fmaf(B1, cx2, A1); e_b3 = __builtin_fmaf(B1, cx3, A1);
            e_t0 = C1 * cy0; e_t1 = C1 * cy1; e_t2 = C1 * cy2; e_t3 = C1 * cy3;
            bn[1][0] = fminf(e_b0, e_b1); bX[1][0] = fmaxf(e_b0, e_b1);
            bn[1][1] = fminf(e_b2, e_b3); bX[1][1] = fmaxf(e_b2, e_b3);
            tn[1][0] = fminf(e_t0, e_t1); tX[1][0] = fmaxf(e_t0, e_t1);
            tn[1][1] = fminf(e_t2, e_t3); tX[1][1] = fmaxf(e_t2, e_t3);
            // edge 2
            e_b0 = __builtin_fmaf(B2, cx0, A2); e_b1 = __builtin_fmaf(B2, cx1, A2);
            e_b2 = __builtin_fmaf(B2, cx2, A2); e_b3 = __builtin_fmaf(B2, cx3, A2);
            e_t0 = C2 * cy0; e_t1 = C2 * cy1; e_t2 = C2 * cy2; e_t3 = C2 * cy3;
            bn[2][0] = fminf(e_b0, e_b1); bX[2][0] = fmaxf(e_b0, e_b1);
            bn[2][1] = fminf(e_b2, e_b3); bX[2][1] = fmaxf(e_b2, e_b3);
            tn[2][0] = fminf(e_t0, e_t1); tX[2][0] = fmaxf(e_t0, e_t1);
            tn[2][1] = fminf(e_t2, e_t3); tX[2][1] = fmaxf(e_t2, e_t3);
        }
        // z bounds (separable)
        float zb0 = __builtin_fmaf(Zx, cx0, Z0), zb1 = __builtin_fmaf(Zx, cx1, Z0);
        float zb2 = __builtin_fmaf(Zx, cx2, Z0), zb3 = __builtin_fmaf(Zx, cx3, Z0);
        float zt0 = Zy * cy0, zt1 = Zy * cy1, zt2 = Zy * cy2, zt3 = Zy * cy3;
        float zbX0 = fmaxf(zb0, zb1), zbX1 = fmaxf(zb2, zb3);
        float ztX0 = fmaxf(zt0, zt1), ztX1 = fmaxf(zt2, zt3);
        float zbN0 = fminf(zb0, zb1), zbN1 = fminf(zb2, zb3);
        float ztN0 = fminf(zt0, zt1), ztN1 = fminf(zt2, zt3);

        int partMask = 0;
        float key0f = 0.0f, key1f = 0.0f, key2f = 0.0f, key3f = 0.0f;

        #pragma unroll
        for (int q = 0; q < 4; ++q) {
            const int qx = q & 1, qy = q >> 1;
            const int qj0 = rj0 + qx * 16, qi0 = ri0 + qy * 16;
            if (jlo > qj0 + 15 || jhi < qj0 || ilo > qi0 + 15 || ihi < qi0) continue;
            float e0x = bX[0][qx] + tX[0][qy];
            float e1x = bX[1][qx] + tX[1][qy];
            float e2x = bX[2][qx] + tX[2][qy];
            if (e0x < -Rm || e1x < -Rm || e2x < -Rm) continue;   // quadrant fully outside
            float km = (qx ? zbX1 : zbX0) + (qy ? ztX1 : ztX0);
            float key = fmaxf(km + __builtin_fmaf(fabsf(km), 1e-6f, 1e-5f), 0.0f);
            float e0n = bn[0][qx] + tn[0][qy];
            float e1n = bn[1][qx] + tn[1][qy];
            float e2n = bn[2][qx] + tn[2][qy];
            bool full = (e0n > Rm) && (e1n > Rm) && (e2n > Rm);
            if (full) {
                // raise quadrant occlusion floor with conservative zmin lower bound
                float zmn = (qx ? zbN1 : zbN0) + (qy ? ztN1 : ztN0);
                float thrv = zmn - __builtin_fmaf(fabsf(zmn), 1e-6f, 1e-5f);
                if (thrv > 0.0f) atomicMax(&thrq[q], __float_as_uint(thrv));
                int s = atomicAdd(&qfcnt[q], 1);
                if (s < CAPFQ) { qfull[q][s] = make_float4(Z0, Zx, Zy, key); continue; }
            }
            partMask |= 1 << q;
            if (q == 0) key0f = key; else if (q == 1) key1f = key;
            else if (q == 2) key2f = key; else key3f = key;
        }

        if (partMask) {
            int p = atomicAdd(&cnt_p, 1);
            if (p < CAPP) {
                pool[2 * p + 0] = P.q0;
                pool[2 * p + 1] = P.q1;   // B1,C1,Zx,Zy
                uint32_t efh = (uint32_t)__half_as_ushort(__float2half(ef * 1.002f));
                zef[p] = make_uint2(__float_as_uint(Z0), ((uint32_t)f << 16) | efh);
                #pragma unroll
                for (int q = 0; q < 4; ++q) {
                    if (!((partMask >> q) & 1)) continue;
                    float key = (q == 0) ? key0f : (q == 1) ? key1f : (q == 2) ? key2f : key3f;
                    uint32_t entry = ((__float_as_uint(key) + 0xFFFu) & 0xFFFFF000u) | (uint32_t)p;
                    int s = atomicAdd(&qcnt[q], 1);
                    if (s < CAPQ) qpart[q][s] = entry;
                    else { int o = atomicAdd(&cnt_o, 1); if (o < OVN) ovl[o] = (uint16_t)f; }
                }
            } else {
                int o = atomicAdd(&cnt_o, 1);
                if (o < OVN) ovl[o] = (uint16_t)f;
            }
        }
    }
    __syncthreads();

    const int no = min(cnt_o, OVN);
    // pad quadrant partial lists to multiple of 4 with 0 (keybits 0 -> always skipped)
    #pragma unroll
    for (int q = 0; q < 4; ++q) {
        int n = min(qcnt[q], CAPQ); int n4 = (n + 3) & ~3;
        for (int i = n + tid; i < n4; i += 256) qpart[q][i] = 0u;
    }
    __syncthreads();

    // ---- phase 2 ----
    const int lane = tid & 63, w = tid >> 6;
    const int wj0 = rj0 + ((w & 1) << 4);
    const int wi0 = ri0 + ((w >> 1) << 4);
    const int j = wj0 + (lane & 15);
    const int i0r = wi0 + (lane >> 4);                 // rows i0r + 4r
    const float px = (float)(2 * j + 1 - SS) * (1.0f / SS);
    const float py0 = (float)(SS - 1 - 2 * (i0r + 0))  * (1.0f / SS);
    const float py1 = (float)(SS - 1 - 2 * (i0r + 4))  * (1.0f / SS);
    const float py2 = (float)(SS - 1 - 2 * (i0r + 8))  * (1.0f / SS);
    const float py3 = (float)(SS - 1 - 2 * (i0r + 12)) * (1.0f / SS);

    const size_t obase = (size_t)b * (SS * SS) + (size_t)i0r * SS + j;

    // skip floor: within-chunk full-face threshold + cross-chunk zu snapshot.
    // zu is monotone-decreasing; a snapshot value was achieved by some write, so
    // skipping faces with key <= floor cannot change any atomicMin outcome.
    // FIX vs R11: lane floor = 1/(MAX z over its 4 rows), valid ONLY if all 4
    // rows are already written; else 0 (no bound). R11 used min -> wrong skips.
    float floorf_;
    {
        float s = __uint_as_float(thrq[w]);
        uint32_t u0v = zu[obase + 0 * 4 * SS];
        uint32_t u1v = zu[obase + 1 * 4 * SS];
        uint32_t u2v = zu[obase + 2 * 4 * SS];
        uint32_t u3v = zu[obase + 3 * 4 * SS];
        bool all4 = (u0v != 0xFFFFFFFFu) && (u1v != 0xFFFFFFFFu) &&
                    (u2v != 0xFFFFFFFFu) && (u3v != 0xFFFFFFFFu);
        float zlane = 0.0f;
        if (all4) {
            float zmax = fmaxf(fmaxf(__uint_as_float(u0v), __uint_as_float(u1v)),
                               fmaxf(__uint_as_float(u2v), __uint_as_float(u3v)));
            zlane = (1.0f / zmax) * 0.9999997f;   // conservative down-round
        }
        floorf_ = fmaxf(s, wave_min_f(zlane));
    }

    float best0 = 0.0f, best1 = 0.0f, best2 = 0.0f, best3 = 0.0f;

    // full-in-quadrant faces first: 16B + ~10 VALU each, raises best for skips
    {
        const float4* qf = &qfull[w][0];
        const int nq = min(qfcnt[w], CAPFQ);
        float lm = floorf_;
        for (int k = 0; k < nq; ++k) {
            if ((k & 15) == 0)
                lm = fmaxf(floorf_, wave_min_f(fminf(fminf(best0, best1), fminf(best2, best3))));
            float4 z = qf[k];
            if (z.w <= lm) continue;
            float zb = __builtin_fmaf(z.y, px, z.x);
            best0 = fmaxf(best0, __builtin_fmaf(z.z, py0, zb));
            best1 = fmaxf(best1, __builtin_fmaf(z.z, py1, zb));
            best2 = fmaxf(best2, __builtin_fmaf(z.z, py2, zb));
            best3 = fmaxf(best3, __builtin_fmaf(z.z, py3, zb));
        }
    }

    // partial faces: this wave's quadrant list; grouped key skip + deferred amb
    int dcnt = 0;
    {
        const uint32_t* ql = &qpart[w][0];
        const int nq = min(qcnt[w], CAPQ);
        const int nq4 = (nq + 3) & ~3;
        for (int base = 0; base < nq4; base += 16) {
            float lm = fmaxf(floorf_, wave_min_f(fminf(fminf(best0, best1), fminf(best2, best3))));
            uint32_t lmU = __float_as_uint(lm);
            int gend = min(base + 16, nq4);
            for (int g = base; g < gend; g += 4) {
                uint4 kk = *reinterpret_cast<const uint4*>(&ql[g]);
                uint32_t k0 = kk.x & 0xFFFFF000u, k1 = kk.y & 0xFFFFF000u;
                uint32_t k2 = kk.z & 0xFFFFF000u, k3 = kk.w & 0xFFFFF000u;
                uint32_t gmax = max(max(k0, k1), max(k2, k3));
                if (gmax <= lmU) continue;                 // uniform: skip 4 faces
                #pragma unroll
                for (int u = 0; u < 4; ++u) {
                    uint32_t e = (u == 0) ? kk.x : (u == 1) ? kk.y : (u == 2) ? kk.z : kk.w;
                    if ((e & 0xFFFFF000u) <= lmU) continue;   // uniform
                    int k = (int)(e & 0xFFFu);
                    float4 q0 = pool[2 * k + 0];
                    float4 q1 = pool[2 * k + 1];
                    uint2  ze = zef[k];
                    float Z0 = __uint_as_float(ze.x);
                    float ef = __half2float(__ushort_as_half((unsigned short)(ze.y & 0xFFFFu)));
                    float w0b = __builtin_fmaf(q0.y, px, q0.x);
                    float w1b = __builtin_fmaf(q1.x, px, q0.w);
                    float zbv = __builtin_fmaf(q1.z, px, Z0);
                    float w0_0 = __builtin_fmaf(q0.z, py0, w0b), w1_0 = __builtin_fmaf(q1.y, py0, w1b);
                    float w0_1 = __builtin_fmaf(q0.z, py1, w0b), w1_1 = __builtin_fmaf(q1.y, py1, w1b);
                    float w0_2 = __builtin_fmaf(q0.z, py2, w0b), w1_2 = __builtin_fmaf(q1.y, py2, w1b);
                    float w0_3 = __builtin_fmaf(q0.z, py3, w0b), w1_3 = __builtin_fmaf(q1.y, py3, w1b);
                    float m0 = fminf(w0_0, fminf(w1_0, (1.0f - w0_0) - w1_0));
                    float m1 = fminf(w0_1, fminf(w1_1, (1.0f - w0_1) - w1_1));
                    float m2 = fminf(w0_2, fminf(w1_2, (1.0f - w0_2) - w1_2));
                    float m3 = fminf(w0_3, fminf(w1_3, (1.0f - w0_3) - w1_3));
                    float zi0 = __builtin_fmaf(q1.w, py0, zbv);
                    float zi1 = __builtin_fmaf(q1.w, py1, zbv);
                    float zi2 = __builtin_fmaf(q1.w, py2, zbv);
                    float zi3 = __builtin_fmaf(q1.w, py3, zbv);
                    best0 = (m0 > ef) ? fmaxf(best0, zi0) : best0;
                    best1 = (m1 > ef) ? fmaxf(best1, zi1) : best1;
                    best2 = (m2 > ef) ? fmaxf(best2, zi2) : best2;
                    best3 = (m3 > ef) ? fmaxf(best3, zi3) : best3;
                    float mabs = fminf(fminf(fabsf(m0), fabsf(m1)), fminf(fabsf(m2), fabsf(m3)));
                    if (__any(mabs <= ef)) {
                        if (dcnt == DEFN) {
                            for (int d = 0; d < dcnt; ++d) {
                                int kk2 = (int)dlist[w][d];
                                float4 p1 = pool[2 * kk2 + 1];
                                uint2  z2 = zef[kk2];
                                exact_body(p1.z, p1.w, __uint_as_float(z2.x), (int)(z2.y >> 16),
                                           px, py0, py1, py2, py3, verts, faces, N, b,
                                           best0, best1, best2, best3);
                            }
                            dcnt = 0;
                        }
                        if (lane == 0) dlist[w][dcnt] = (uint16_t)k;
                        dcnt++;
                    }
                }
            }
        }
    }
    // drain deferred faces (exact decisions in the +-ef band)
    for (int d = 0; d < dcnt; ++d) {
        int kk2 = (int)dlist[w][d];
        float4 p1 = pool[2 * kk2 + 1];
        uint2  z2 = zef[kk2];
        exact_body(p1.z, p1.w, __uint_as_float(z2.x), (int)(z2.y >> 16),
                   px, py0, py1, py2, py3, verts, faces, N, b,
                   best0, best1, best2, best3);
    }

    // overflow faces (rare): direct from global; idempotent wrt list paths
    const PackedCoef* pb2 = pc + (size_t)b * F;
    for (int k = 0; k < no; ++k) {
        int fid = __builtin_amdgcn_readfirstlane((int)ovl[k]);
        float4 q2 = pb2[fid].q2;
        uint32_t bv = __float_as_uint(q2.z);
        int jlo = bv & 255, jhi = (bv >> 8) & 255, ilo = (bv >> 16) & 255, ihi = (int)(bv >> 24);
        if (jlo > wj0 + 15 || jhi < wj0 || ilo > wi0 + 15 || ihi < wi0) continue;
        face_body(pb2[fid].q0, pb2[fid].q1, q2,
                  px, py0, py1, py2, py3, verts, faces, N, b,
                  best0, best1, best2, best3);
    }

    if (best0 > 0.0f) atomicMin(&zu[obase + 0 * 4 * SS], __float_as_uint(1.0f / best0));
    if (best1 > 0.0f) atomicMin(&zu[obase + 1 * 4 * SS], __float_as_uint(1.0f / best1));
    if (best2 > 0.0f) atomicMin(&zu[obase + 2 * 4 * SS], __float_as_uint(1.0f / best2));
    if (best3 > 0.0f) atomicMin(&zu[obase + 3 * 4 * SS], __float_as_uint(1.0f / best3));
}

// ---------------- final: uint zbuf -> (sil, z) ----------------
__global__ void nmr_final(float* __restrict__ out, int B)
{
    int idx = blockIdx.x * 256 + threadIdx.x;
    if (idx >= B * SS * SS) return;
    uint32_t* zu = (uint32_t*)(out + (size_t)B * SS * SS);
    uint32_t u = zu[idx];
    bool cov = (u != 0xFFFFFFFFu);
    out[idx] = cov ? 1.0f : 0.0f;
    ((float*)zu)[idx] = cov ? __uint_as_float(u) : FAR_F;
}

// ---------------- host ----------------
extern "C" void kernel_launch(void* const* d_in, const int* in_sizes, int n_in,
                              void* d_out, int out_size, void* d_ws, size_t ws_size,
                              hipStream_t stream)
{
    const float* verts = (const float*)d_in[0];
    const int*   faces = (const int*)d_in[1];
    float* out = (float*)d_out;

    const int B = out_size / (2 * SS * SS);          // 16
    const int F = in_sizes[1] / 3;                   // 1538
    const int N = in_sizes[0] / (3 * B);             // 778

    PackedCoef* pc = (PackedCoef*)d_ws;
    uint32_t*  bbx = (uint32_t*)((char*)d_ws + (size_t)B * F * sizeof(PackedCoef));
    uint32_t*  zu  = (uint32_t*)(out + (size_t)B * SS * SS);

    hipMemsetAsync(zu, 0xFF, (size_t)B * SS * SS * sizeof(uint32_t), stream);

    const int total = B * F;
    nmr_prep<<<(total + 255) / 256, 256, 0, stream>>>(verts, faces, pc, bbx, B, N, F);

    const int CH = (F + NCH - 1) / NCH;              // 513
    nmr_raster<<<B * NREG * NCH, 256, 0, stream>>>(pc, bbx, verts, faces, zu, B, N, F, CH);

    nmr_final<<<(B * SS * SS + 255) / 256, 256, 0, stream>>>(out, B);
}

// Round 13
// 76.376 us; speedup vs baseline: 1.0664x; 1.0664x over previous
//
#include <hip/hip_runtime.h>
#include <hip/hip_fp16.h>
#include <stdint.h>

#define SS 256
#define FAR_F 100.0f
#define REG 32             // region size in px
#define NREG 64            // regions per batch (8x8)
#define NCH 3              // face chunks
#define CAPP 448           // partial-face pool capacity
#define CAPQ 320           // per-quadrant partial list capacity (multiple of 4)
#define CAPFQ 192          // per-quadrant full list capacity
#define OVN  96            // overflow capacity
#define DEFN 32            // per-wave deferred-ambiguity capacity

struct __align__(16) PackedCoef {
    float4 q0;  // A0,B0,C0,A1   (edge coefs premultiplied by inv_area)
    float4 q1;  // B1,C1,Zx,Zy   (zinv = Z0 + Zx*px + Zy*py)
    float4 q2;  // Z0, e_face, bits(bbox), bits(faceid)
};

// ---------------- prep: per (b,f) packed coefficients + bbox ----------------
__global__ void nmr_prep(const float* __restrict__ verts,
                         const int* __restrict__ faces,
                         PackedCoef* __restrict__ pc,
                         uint32_t* __restrict__ bbx,
                         int B, int N, int F)
{
#pragma clang fp contract(off)
    int idx = blockIdx.x * blockDim.x + threadIdx.x;
    if (idx >= B * F) return;
    int b = idx / F;
    int f = idx - b * F;

    int i0 = faces[3 * f + 0], i1 = faces[3 * f + 1], i2 = faces[3 * f + 2];
    const float* vb = verts + (size_t)(3 * N) * b;
    const float EZ = -1.7320508075688772f;  // f32(EYE_Z)

    float x0 = vb[3 * i0 + 0], y0 = -vb[3 * i0 + 1], z0 = vb[3 * i0 + 2] - EZ;
    float x1 = vb[3 * i1 + 0], y1 = -vb[3 * i1 + 1], z1 = vb[3 * i1 + 2] - EZ;
    float x2 = vb[3 * i2 + 0], y2 = -vb[3 * i2 + 1], z2 = vb[3 * i2 + 2] - EZ;

    float area = (x1 - x0) * (y2 - y0) - (x2 - x0) * (y1 - y0);
    bool ok = fabsf(area) > 1e-7f;
    float ia = ok ? (1.0f / area) : 0.0f;

    float A0 = (x1 * y2 - x2 * y1) * ia, B0 = (y1 - y2) * ia, C0 = (x2 - x1) * ia;
    float A1 = (x2 * y0 - x0 * y2) * ia, B1 = (y2 - y0) * ia, C1 = (x0 - x2) * ia;
    float rz0 = 1.0f / z0, rz1 = 1.0f / z1, rz2 = 1.0f / z2;
    float d0 = rz0 - rz2, d1 = rz1 - rz2;
    float Z0 = rz2 + A0 * d0 + A1 * d1;
    float Zx = B0 * d0 + B1 * d1;
    float Zy = C0 * d0 + C1 * d1;
    // rigorous per-face ambiguity half-width (|px|,|py|<1)
    float S = fabsf(A0) + fabsf(B0) + fabsf(C0) + fabsf(A1) + fabsf(B1) + fabsf(C1) + 1.0f;
    float ef = 3e-6f * S;

    uint32_t bb = 255u | (0u << 8) | (255u << 16) | (0u << 24);
    if (ok) {
        float xmn = fminf(x0, fminf(x1, x2)), xmx = fmaxf(x0, fmaxf(x1, x2));
        float ymn = fminf(y0, fminf(y1, y2)), ymx = fmaxf(y0, fmaxf(y1, y2));
        int jlo = (int)floorf(128.0f * (xmn + 1.0f) - 0.5f) - 1;
        int jhi = (int)ceilf (128.0f * (xmx + 1.0f) - 0.5f) + 1;
        int ilo = (int)floorf((255.0f - 256.0f * ymx) * 0.5f) - 1;
        int ihi = (int)ceilf ((255.0f - 256.0f * ymn) * 0.5f) + 1;
        jlo = max(0, min(255, jlo)); jhi = max(0, min(255, jhi));
        ilo = max(0, min(255, ilo)); ihi = max(0, min(255, ihi));
        if (jhi >= jlo && ihi >= ilo)
            bb = (uint32_t)jlo | ((uint32_t)jhi << 8) | ((uint32_t)ilo << 16) | ((uint32_t)ihi << 24);
    }

    PackedCoef c;
    c.q0 = make_float4(A0, B0, C0, A1);
    c.q1 = make_float4(B1, C1, Zx, Zy);
    c.q2 = make_float4(Z0, ef, __uint_as_float(bb), __uint_as_float((uint32_t)f));
    pc[idx] = c;
    bbx[idx] = bb;
}

// exact numpy-order decision + accumulate (deferred-ambiguity / amb paths)
__device__ __forceinline__ void exact_body(
    float Zx, float Zy, float Z0, int fid,
    float px, float py0, float py1, float py2, float py3,
    const float* __restrict__ verts, const int* __restrict__ faces, int N, int b,
    float& best0, float& best1, float& best2, float& best3)
{
#pragma clang fp contract(off)
    float zbv = __builtin_fmaf(Zx, px, Z0);
    float zi0 = __builtin_fmaf(Zy, py0, zbv);
    float zi1 = __builtin_fmaf(Zy, py1, zbv);
    float zi2 = __builtin_fmaf(Zy, py2, zbv);
    float zi3 = __builtin_fmaf(Zy, py3, zbv);
    fid = __builtin_amdgcn_readfirstlane(fid);
    int i0f = faces[3 * fid + 0], i1f = faces[3 * fid + 1], i2f = faces[3 * fid + 2];
    const float* vb = verts + (size_t)(3 * N) * b;
    float x0 = vb[3 * i0f + 0], y0 = -vb[3 * i0f + 1];
    float x1 = vb[3 * i1f + 0], y1 = -vb[3 * i1f + 1];
    float x2 = vb[3 * i2f + 0], y2 = -vb[3 * i2f + 1];
    float area = (x1 - x0) * (y2 - y0) - (x2 - x0) * (y1 - y0);
    float ia = 1.0f / area;   // staged faces are non-degenerate
    float a0 = x1 * y2 - x2 * y1, b0e = y1 - y2, c0e = x2 - x1;
    float a1 = x2 * y0 - x0 * y2, b1e = y2 - y0, c1e = x0 - x2;
    float e0b = a0 + b0e * px;
    float e1b = a1 + b1e * px;
    { float u0 = (e0b + c0e * py0) * ia, u1 = (e1b + c1e * py0) * ia;
      if (fminf(u0, fminf(u1, (1.0f - u0) - u1)) >= 0.0f) best0 = fmaxf(best0, zi0); }
    { float u0 = (e0b + c0e * py1) * ia, u1 = (e1b + c1e * py1) * ia;
      if (fminf(u0, fminf(u1, (1.0f - u0) - u1)) >= 0.0f) best1 = fmaxf(best1, zi1); }
    { float u0 = (e0b + c0e * py2) * ia, u1 = (e1b + c1e * py2) * ia;
      if (fminf(u0, fminf(u1, (1.0f - u0) - u1)) >= 0.0f) best2 = fmaxf(best2, zi2); }
    { float u0 = (e0b + c0e * py3) * ia, u1 = (e1b + c1e * py3) * ia;
      if (fminf(u0, fminf(u1, (1.0f - u0) - u1)) >= 0.0f) best3 = fmaxf(best3, zi3); }
}

// full body from global records (overflow path only)
__device__ __forceinline__ void face_body(
    float4 q0, float4 q1, float4 q2,
    float px, float py0, float py1, float py2, float py3,
    const float* __restrict__ verts, const int* __restrict__ faces, int N, int b,
    float& best0, float& best1, float& best2, float& best3)
{
#pragma clang fp contract(off)
    const float ef = q2.y;
    float w0b = __builtin_fmaf(q0.y, px, q0.x);
    float w1b = __builtin_fmaf(q1.x, px, q0.w);
    float zbv = __builtin_fmaf(q1.z, px, q2.x);
    float w0_0 = __builtin_fmaf(q0.z, py0, w0b), w1_0 = __builtin_fmaf(q1.y, py0, w1b);
    float w0_1 = __builtin_fmaf(q0.z, py1, w0b), w1_1 = __builtin_fmaf(q1.y, py1, w1b);
    float w0_2 = __builtin_fmaf(q0.z, py2, w0b), w1_2 = __builtin_fmaf(q1.y, py2, w1b);
    float w0_3 = __builtin_fmaf(q0.z, py3, w0b), w1_3 = __builtin_fmaf(q1.y, py3, w1b);
    float m0 = fminf(w0_0, fminf(w1_0, (1.0f - w0_0) - w1_0));
    float m1 = fminf(w0_1, fminf(w1_1, (1.0f - w0_1) - w1_1));
    float m2 = fminf(w0_2, fminf(w1_2, (1.0f - w0_2) - w1_2));
    float m3 = fminf(w0_3, fminf(w1_3, (1.0f - w0_3) - w1_3));
    float zi0 = __builtin_fmaf(q1.w, py0, zbv);
    float zi1 = __builtin_fmaf(q1.w, py1, zbv);
    float zi2 = __builtin_fmaf(q1.w, py2, zbv);
    float zi3 = __builtin_fmaf(q1.w, py3, zbv);
    bool amb = (fabsf(m0) <= ef) | (fabsf(m1) <= ef) | (fabsf(m2) <= ef) | (fabsf(m3) <= ef);
    if (__any(amb)) {
        exact_body(q1.z, q1.w, q2.x, (int)__float_as_uint(q2.w),
                   px, py0, py1, py2, py3, verts, faces, N, b, best0, best1, best2, best3);
        return;
    }
    best0 = (m0 > ef) ? fmaxf(best0, zi0) : best0;
    best1 = (m1 > ef) ? fmaxf(best1, zi1) : best1;
    best2 = (m2 > ef) ? fmaxf(best2, zi2) : best2;
    best3 = (m3 > ef) ? fmaxf(best3, zi3) : best3;
}

__device__ __forceinline__ float wave_min_f(float x) {
    #pragma unroll
    for (int m = 1; m < 64; m <<= 1) x = fminf(x, __shfl_xor(x, m));
    return x;
}

// in-register bitonic sort of 64 u32 across the wave, DESCENDING
__device__ __forceinline__ uint32_t wave_sort64_desc(uint32_t e) {
    const int lane = (int)(threadIdx.x & 63);
    #pragma unroll
    for (int k = 2; k <= 64; k <<= 1) {
        #pragma unroll
        for (int j = k >> 1; j > 0; j >>= 1) {
            uint32_t other = __shfl_xor(e, j);
            int partner = lane ^ j;
            bool up = ((lane & k) != 0);                 // descending overall
            bool keepSmall = ((lane < partner) == up);
            uint32_t mn = min(e, other), mx = max(e, other);
            e = keepSmall ? mn : mx;
        }
    }
    return e;
}

// ---------------- raster: block = (batch, 32x32 region, face-chunk) ----------------
__global__ __launch_bounds__(256, 4) void nmr_raster(
    const PackedCoef* __restrict__ pc,
    const uint32_t* __restrict__ bbx,
    const float* __restrict__ verts,
    const int* __restrict__ faces,
    uint32_t* __restrict__ zu,
    int B, int N, int F, int CH)
{
#pragma clang fp contract(off)
    __shared__ float4   pool[2 * CAPP];               // partial: edge coefs + (B1,C1,Zx,Zy)
    __shared__ uint2    zef[CAPP];                    // partial: Z0 bits, fid<<16|ef_f16
    __shared__ float4   qfull[4][CAPFQ];              // full-in-quadrant: Z0,Zx,Zy,key
    __shared__ __align__(16) uint32_t fkidx[4][CAPFQ];// full: key(hi20)|idx(lo12), sorted desc
    __shared__ __align__(16) uint32_t qpart[4][CAPQ]; // partial: key(hi20)|poolidx, sorted desc
    __shared__ uint16_t ovl[OVN];                     // overflow face ids (global fallback)
    __shared__ uint16_t dlist[4][DEFN];               // per-wave deferred-amb pool idx
    __shared__ int qcnt[4], qfcnt[4], cnt_p, cnt_o;

    const int tid = threadIdx.x;
    const int bid = blockIdx.x;
    const int ch = bid % NCH; int t = bid / NCH;
    const int reg = t % NREG; const int b = t / NREG;
    const int rj0 = (reg & 7) * REG;
    const int ri0 = (reg >> 3) * REG;

    if (tid == 0) { cnt_p = 0; cnt_o = 0; }
    if (tid < 4) { qcnt[tid] = 0; qfcnt[tid] = 0; }
    __syncthreads();

    // ---- phase 1: cull -> per-quadrant classify -> stage ----
    const int f0 = ch * CH, f1 = min(F, f0 + CH);
    const uint32_t* bb = bbx + (size_t)b * F;
    const PackedCoef* pb = pc + (size_t)b * F;

    const float cx0 = (float)(2 * rj0 + 1 - SS) * (1.0f / SS);
    const float cx1 = (float)(2 * (rj0 + 15) + 1 - SS) * (1.0f / SS);
    const float cx2 = (float)(2 * (rj0 + 16) + 1 - SS) * (1.0f / SS);
    const float cx3 = (float)(2 * (rj0 + 31) + 1 - SS) * (1.0f / SS);
    const float cy0 = (float)(SS - 1 - 2 * ri0) * (1.0f / SS);
    const float cy1 = (float)(SS - 1 - 2 * (ri0 + 15)) * (1.0f / SS);
    const float cy2 = (float)(SS - 1 - 2 * (ri0 + 16)) * (1.0f / SS);
    const float cy3 = (float)(SS - 1 - 2 * (ri0 + 31)) * (1.0f / SS);

    for (int f = f0 + tid; f < f1; f += 256) {
        uint32_t v = bb[f];
        int jlo = v & 255, jhi = (v >> 8) & 255, ilo = (v >> 16) & 255, ihi = (int)(v >> 24);
        if (jlo > rj0 + REG - 1 || jhi < rj0 || ilo > ri0 + REG - 1 || ihi < ri0) continue;
        PackedCoef P = pb[f];
        const float A0 = P.q0.x, B0 = P.q0.y, C0 = P.q0.z;
        const float A1 = P.q0.w, B1 = P.q1.x, C1 = P.q1.y;
        const float Zx = P.q1.z, Zy = P.q1.w, Z0 = P.q2.x, ef = P.q2.y;
        const float A2 = (1.0f - A0) - A1, B2 = (0.0f - B0) - B1, C2 = (0.0f - C0) - C1;
        const float Rm = 2.0f * ef;

        // separable per-quadrant bounds for 3 edges
        float bn[3][2], bX[3][2], tn[3][2], tX[3][2];
        {
            float e_b0, e_b1, e_b2, e_b3, e_t0, e_t1, e_t2, e_t3;
            // edge 0
            e_b0 = __builtin_fmaf(B0, cx0, A0); e_b1 = __builtin_fmaf(B0, cx1, A0);
            e_b2 = __builtin_fmaf(B0, cx2, A0); e_b3 = __builtin_fmaf(B0, cx3, A0);
            e_t0 = C0 * cy0; e_t1 = C0 * cy1; e_t2 = C0 * cy2; e_t3 = C0 * cy3;
            bn[0][0] = fminf(e_b0, e_b1); bX[0][0] = fmaxf(e_b0, e_b1);
            bn[0][1] = fminf(e_b2, e_b3); bX[0][1] = fmaxf(e_b2, e_b3);
            tn[0][0] = fminf(e_t0, e_t1); tX[0][0] = fmaxf(e_t0, e_t1);
            tn[0][1] = fminf(e_t2, e_t3); tX[0][1] = fmaxf(e_t2, e_t3);
            // edge 1
            e_b0 = __builtin_fmaf(B1, cx0, A1); e_b1 = __builtin_fmaf(B1, cx1, A1);
            e_b2 = __builtin_fmaf(B1, cx2, A1); e_b3 = __builtin_fmaf(B1, cx3, A1);
            e_t0 = C1 * cy0; e_t1 = C1 * cy1; e_t2 = C1 * cy2; e_t3 = C1 * cy3;
            bn[1][0] = fminf(e_b0, e_b1); bX[1][0] = fmaxf(e_b0, e_b1);
            bn[1][1] = fminf(e_b2, e_b3); bX[1][1] = fmaxf(e_b2, e_b3);
            tn[1][0] = fminf(e_t0, e_t1); tX[1][0] = fmaxf(e_t0, e_t1);
            tn[1][1] = fminf(e_t2, e_t3); tX[1][1] = fmaxf(e_t2, e_t3);
            // edge 2
            e_b0 = __builtin_fmaf(B2, cx0, A2); e_b1 = __builtin_fmaf(B2, cx1, A2);
            e_b2 = __builtin_fmaf(B2, cx2, A2); e_b3 = __builtin_fmaf(B2, cx3, A2);
            e_t0 = C2 * cy0; e_t1 = C2 * cy1; e_t2 = C2 * cy2; e_t3 = C2 * cy3;
            bn[2][0] = fminf(e_b0, e_b1); bX[2][0] = fmaxf(e_b0, e_b1);
            bn[2][1] = fminf(e_b2, e_b3); bX[2][1] = fmaxf(e_b2, e_b3);
            tn[2][0] = fminf(e_t0, e_t1); tX[2][0] = fmaxf(e_t0, e_t1);
            tn[2][1] = fminf(e_t2, e_t3); tX[2][1] = fmaxf(e_t2, e_t3);
        }
        // z upper bounds (separable)
        float zb0 = __builtin_fmaf(Zx, cx0, Z0), zb1 = __builtin_fmaf(Zx, cx1, Z0);
        float zb2 = __builtin_fmaf(Zx, cx2, Z0), zb3 = __builtin_fmaf(Zx, cx3, Z0);
        float zt0 = Zy * cy0, zt1 = Zy * cy1, zt2 = Zy * cy2, zt3 = Zy * cy3;
        float zbX0 = fmaxf(zb0, zb1), zbX1 = fmaxf(zb2, zb3);
        float ztX0 = fmaxf(zt0, zt1), ztX1 = fmaxf(zt2, zt3);

        int partMask = 0;
        float key0f = 0.0f, key1f = 0.0f, key2f = 0.0f, key3f = 0.0f;

        #pragma unroll
        for (int q = 0; q < 4; ++q) {
            const int qx = q & 1, qy = q >> 1;
            const int qj0 = rj0 + qx * 16, qi0 = ri0 + qy * 16;
            if (jlo > qj0 + 15 || jhi < qj0 || ilo > qi0 + 15 || ihi < qi0) continue;
            float e0x = bX[0][qx] + tX[0][qy];
            float e1x = bX[1][qx] + tX[1][qy];
            float e2x = bX[2][qx] + tX[2][qy];
            if (e0x < -Rm || e1x < -Rm || e2x < -Rm) continue;   // quadrant fully outside
            float km = (qx ? zbX1 : zbX0) + (qy ? ztX1 : ztX0);
            float key = fmaxf(km + __builtin_fmaf(fabsf(km), 1e-6f, 1e-5f), 0.0f);
            float e0n = bn[0][qx] + tn[0][qy];
            float e1n = bn[1][qx] + tn[1][qy];
            float e2n = bn[2][qx] + tn[2][qy];
            bool full = (e0n > Rm) && (e1n > Rm) && (e2n > Rm);
            if (full) {
                int s = atomicAdd(&qfcnt[q], 1);
                if (s < CAPFQ) {
                    qfull[q][s] = make_float4(Z0, Zx, Zy, key);
                    fkidx[q][s] = ((__float_as_uint(key) + 0xFFFu) & 0xFFFFF000u) | (uint32_t)s;
                    continue;
                }
            }
            partMask |= 1 << q;
            if (q == 0) key0f = key; else if (q == 1) key1f = key;
            else if (q == 2) key2f = key; else key3f = key;
        }

        if (partMask) {
            int p = atomicAdd(&cnt_p, 1);
            if (p < CAPP) {
                pool[2 * p + 0] = P.q0;
                pool[2 * p + 1] = P.q1;   // B1,C1,Zx,Zy
                uint32_t efh = (uint32_t)__half_as_ushort(__float2half(ef * 1.002f));
                zef[p] = make_uint2(__float_as_uint(Z0), ((uint32_t)f << 16) | efh);
                #pragma unroll
                for (int q = 0; q < 4; ++q) {
                    if (!((partMask >> q) & 1)) continue;
                    float key = (q == 0) ? key0f : (q == 1) ? key1f : (q == 2) ? key2f : key3f;
                    uint32_t entry = ((__float_as_uint(key) + 0xFFFu) & 0xFFFFF000u) | (uint32_t)p;
                    int s = atomicAdd(&qcnt[q], 1);
                    if (s < CAPQ) qpart[q][s] = entry;
                    else { int o = atomicAdd(&cnt_o, 1); if (o < OVN) ovl[o] = (uint16_t)f; }
                }
            } else {
                int o = atomicAdd(&cnt_o, 1);
                if (o < OVN) ovl[o] = (uint16_t)f;
            }
        }
    }
    __syncthreads();

    const int no = min(cnt_o, OVN);
    // pad lists to multiple of 4 with 0 (key 0 -> always skipped / sorts to end)
    #pragma unroll
    for (int q = 0; q < 4; ++q) {
        int n = min(qcnt[q], CAPQ); int n4 = (n + 3) & ~3;
        for (int i = n + tid; i < n4; i += 256) qpart[q][i] = 0u;
        int nf = min(qfcnt[q], CAPFQ); int nf4 = (nf + 3) & ~3;
        for (int i = nf + tid; i < nf4; i += 256) fkidx[q][i] = 0u;
    }
    __syncthreads();

    // ---- phase 2 ----
    const int lane = tid & 63, w = tid >> 6;
    const int wj0 = rj0 + ((w & 1) << 4);
    const int wi0 = ri0 + ((w >> 1) << 4);
    const int j = wj0 + (lane & 15);
    const int i0r = wi0 + (lane >> 4);                 // rows i0r + 4r
    const float px = (float)(2 * j + 1 - SS) * (1.0f / SS);
    const float py0 = (float)(SS - 1 - 2 * (i0r + 0))  * (1.0f / SS);
    const float py1 = (float)(SS - 1 - 2 * (i0r + 4))  * (1.0f / SS);
    const float py2 = (float)(SS - 1 - 2 * (i0r + 8))  * (1.0f / SS);
    const float py3 = (float)(SS - 1 - 2 * (i0r + 12)) * (1.0f / SS);

    // per-wave sort of own lists, descending (64-entry windows, shuffle bitonic;
    // no barriers: each wave owns its quadrant's lists exclusively)
    const int nq  = min(qcnt[w], CAPQ);  const int nq4 = (nq + 3) & ~3;
    const int nfq = min(qfcnt[w], CAPFQ); const int nf4 = (nfq + 3) & ~3;
    for (int wb = 0; wb < nq4; wb += 64) {
        int ix = wb + lane;
        uint32_t e = (ix < nq4) ? qpart[w][ix] : 0u;
        e = wave_sort64_desc(e);
        if (ix < nq4) qpart[w][ix] = e;
    }
    for (int wb = 0; wb < nf4; wb += 64) {
        int ix = wb + lane;
        uint32_t e = (ix < nf4) ? fkidx[w][ix] : 0u;
        e = wave_sort64_desc(e);
        if (ix < nf4) fkidx[w][ix] = e;
    }

    float best0 = 0.0f, best1 = 0.0f, best2 = 0.0f, best3 = 0.0f;

    // full-in-quadrant faces, front-to-back with window break
    {
        const uint32_t* fl = &fkidx[w][0];
        const float4* qf = &qfull[w][0];
        float lm = 0.0f; uint32_t lmU = 0u;
        int cnt = 0;
        for (int wb = 0; wb < nf4; wb += 64) {
            int wend = min(wb + 64, nf4);
            for (int g = wb; g < wend; g += 4) {
                if ((cnt++ & 3) == 0) {
                    lm = wave_min_f(fminf(fminf(best0, best1), fminf(best2, best3)));
                    lmU = __float_as_uint(lm);
                }
                uint4 kk = *reinterpret_cast<const uint4*>(&fl[g]);
                if ((kk.x & 0xFFFFF000u) <= lmU) break;   // descending: rest of window occluded
                #pragma unroll
                for (int u = 0; u < 4; ++u) {
                    uint32_t e = (u == 0) ? kk.x : (u == 1) ? kk.y : (u == 2) ? kk.z : kk.w;
                    if ((e & 0xFFFFF000u) <= lmU) continue;
                    float4 z = qf[e & 0xFFFu];
                    float zb = __builtin_fmaf(z.y, px, z.x);
                    best0 = fmaxf(best0, __builtin_fmaf(z.z, py0, zb));
                    best1 = fmaxf(best1, __builtin_fmaf(z.z, py1, zb));
                    best2 = fmaxf(best2, __builtin_fmaf(z.z, py2, zb));
                    best3 = fmaxf(best3, __builtin_fmaf(z.z, py3, zb));
                }
            }
        }
    }

    // partial faces, front-to-back with window break + deferred amb
    int dcnt = 0;
    {
        const uint32_t* ql = &qpart[w][0];
        float lm = wave_min_f(fminf(fminf(best0, best1), fminf(best2, best3)));
        uint32_t lmU = __float_as_uint(lm);
        int cnt = 0;
        for (int wb = 0; wb < nq4; wb += 64) {
            int wend = min(wb + 64, nq4);
            for (int g = wb; g < wend; g += 4) {
                if ((cnt++ & 3) == 0) {
                    lm = wave_min_f(fminf(fminf(best0, best1), fminf(best2, best3)));
                    lmU = __float_as_uint(lm);
                }
                uint4 kk = *reinterpret_cast<const uint4*>(&ql[g]);
                if ((kk.x & 0xFFFFF000u) <= lmU) break;   // descending window -> done
                #pragma unroll
                for (int u = 0; u < 4; ++u) {
                    uint32_t e = (u == 0) ? kk.x : (u == 1) ? kk.y : (u == 2) ? kk.z : kk.w;
                    if ((e & 0xFFFFF000u) <= lmU) continue;
                    int k = (int)(e & 0xFFFu);
                    float4 q0 = pool[2 * k + 0];
                    float4 q1 = pool[2 * k + 1];
                    uint2  ze = zef[k];
                    float Z0 = __uint_as_float(ze.x);
                    float ef = __half2float(__ushort_as_half((unsigned short)(ze.y & 0xFFFFu)));
                    float w0b = __builtin_fmaf(q0.y, px, q0.x);
                    float w1b = __builtin_fmaf(q1.x, px, q0.w);
                    float zbv = __builtin_fmaf(q1.z, px, Z0);
                    float w0_0 = __builtin_fmaf(q0.z, py0, w0b), w1_0 = __builtin_fmaf(q1.y, py0, w1b);
                    float w0_1 = __builtin_fmaf(q0.z, py1, w0b), w1_1 = __builtin_fmaf(q1.y, py1, w1b);
                    float w0_2 = __builtin_fmaf(q0.z, py2, w0b), w1_2 = __builtin_fmaf(q1.y, py2, w1b);
                    float w0_3 = __builtin_fmaf(q0.z, py3, w0b), w1_3 = __builtin_fmaf(q1.y, py3, w1b);
                    float m0 = fminf(w0_0, fminf(w1_0, (1.0f - w0_0) - w1_0));
                    float m1 = fminf(w0_1, fminf(w1_1, (1.0f - w0_1) - w1_1));
                    float m2 = fminf(w0_2, fminf(w1_2, (1.0f - w0_2) - w1_2));
                    float m3 = fminf(w0_3, fminf(w1_3, (1.0f - w0_3) - w1_3));
                    float zi0 = __builtin_fmaf(q1.w, py0, zbv);
                    float zi1 = __builtin_fmaf(q1.w, py1, zbv);
                    float zi2 = __builtin_fmaf(q1.w, py2, zbv);
                    float zi3 = __builtin_fmaf(q1.w, py3, zbv);
                    best0 = (m0 > ef) ? fmaxf(best0, zi0) : best0;
                    best1 = (m1 > ef) ? fmaxf(best1, zi1) : best1;
                    best2 = (m2 > ef) ? fmaxf(best2, zi2) : best2;
                    best3 = (m3 > ef) ? fmaxf(best3, zi3) : best3;
                    float mabs = fminf(fminf(fabsf(m0), fabsf(m1)), fminf(fabsf(m2), fabsf(m3)));
                    if (__any(mabs <= ef)) {
                        if (dcnt == DEFN) {
                            for (int d = 0; d < dcnt; ++d) {
                                int kk2 = (int)dlist[w][d];
                                float4 p1 = pool[2 * kk2 + 1];
                                uint2  z2 = zef[kk2];
                                exact_body(p1.z, p1.w, __uint_as_float(z2.x), (int)(z2.y >> 16),
                                           px, py0, py1, py2, py3, verts, faces, N, b,
                                           best0, best1, best2, best3);
                            }
                            dcnt = 0;
                        }
                        if (lane == 0) dlist[w][dcnt] = (uint16_t)k;
                        dcnt++;
                    }
                }
            }
        }
    }
    // drain deferred faces (exact decisions in the +-ef band)
    for (int d = 0; d < dcnt; ++d) {
        int kk2 = (int)dlist[w][d];
        float4 p1 = pool[2 * kk2 + 1];
        uint2  z2 = zef[kk2];
        exact_body(p1.z, p1.w, __uint_as_float(z2.x), (int)(z2.y >> 16),
                   px, py0, py1, py2, py3, verts, faces, N, b,
                   best0, best1, best2, best3);
    }

    // overflow faces (rare): direct from global; idempotent wrt list paths
    const PackedCoef* pb2 = pc + (size_t)b * F;
    for (int k = 0; k < no; ++k) {
        int fid = __builtin_amdgcn_readfirstlane((int)ovl[k]);
        float4 q2 = pb2[fid].q2;
        uint32_t bv = __float_as_uint(q2.z);
        int jlo = bv & 255, jhi = (bv >> 8) & 255, ilo = (bv >> 16) & 255, ihi = (int)(bv >> 24);
        if (jlo > wj0 + 15 || jhi < wj0 || ilo > wi0 + 15 || ihi < wi0) continue;
        face_body(pb2[fid].q0, pb2[fid].q1, q2,
                  px, py0, py1, py2, py3, verts, faces, N, b,
                  best0, best1, best2, best3);
    }

    const size_t obase = (size_t)b * (SS * SS) + (size_t)i0r * SS + j;
    if (best0 > 0.0f) atomicMin(&zu[obase + 0 * 4 * SS], __float_as_uint(1.0f / best0));
    if (best1 > 0.0f) atomicMin(&zu[obase + 1 * 4 * SS], __float_as_uint(1.0f / best1));
    if (best2 > 0.0f) atomicMin(&zu[obase + 2 * 4 * SS], __float_as_uint(1.0f / best2));
    if (best3 > 0.0f) atomicMin(&zu[obase + 3 * 4 * SS], __float_as_uint(1.0f / best3));
}

// ---------------- final: uint zbuf -> (sil, z) ----------------
__global__ void nmr_final(float* __restrict__ out, int B)
{
    int idx = blockIdx.x * 256 + threadIdx.x;
    if (idx >= B * SS * SS) return;
    uint32_t* zu = (uint32_t*)(out + (size_t)B * SS * SS);
    uint32_t u = zu[idx];
    bool cov = (u != 0xFFFFFFFFu);
    out[idx] = cov ? 1.0f : 0.0f;
    ((float*)zu)[idx] = cov ? __uint_as_float(u) : FAR_F;
}

// ---------------- host ----------------
extern "C" void kernel_launch(void* const* d_in, const int* in_sizes, int n_in,
                              void* d_out, int out_size, void* d_ws, size_t ws_size,
                              hipStream_t stream)
{
    const float* verts = (const float*)d_in[0];
    const int*   faces = (const int*)d_in[1];
    float* out = (float*)d_out;

    const int B = out_size / (2 * SS * SS);          // 16
    const int F = in_sizes[1] / 3;                   // 1538
    const int N = in_sizes[0] / (3 * B);             // 778

    PackedCoef* pc = (PackedCoef*)d_ws;
    uint32_t*  bbx = (uint32_t*)((char*)d_ws + (size_t)B * F * sizeof(PackedCoef));
    uint32_t*  zu  = (uint32_t*)(out + (size_t)B * SS * SS);

    hipMemsetAsync(zu, 0xFF, (size_t)B * SS * SS * sizeof(uint32_t), stream);

    const int total = B * F;
    nmr_prep<<<(total + 255) / 256, 256, 0, stream>>>(verts, faces, pc, bbx, B, N, F);

    const int CH = (F + NCH - 1) / NCH;              // 513
    nmr_raster<<<B * NREG * NCH, 256, 0, stream>>>(pc, bbx, verts, faces, zu, B, N, F, CH);

    nmr_final<<<(B * SS * SS + 255) / 256, 256, 0, stream>>>(out, B);
}